// Round 16
// baseline (2761.463 us; speedup 1.0000x reference)
//
#include <hip/hip_runtime.h>
#include <hip/hip_bf16.h>

#define T_STEPS 128
#define B_SZ    1024
#define IN_SZ   47
#define H_SZ    646
#define OUT_SZ  5

#define XK    96      // xs padded row stride (47 -> 96)
#define K0    768     // layer0 K = 96 + 672
#define K1    1344    // layer1 K = 672 + 672 (also the state-slab row stride)
#define N0PAD 704     // L0 packed-W cols (11 * 64, zero-padded)
#define N1PAD 672     // L1 packed-W cols
#define RING  4       // L2-resident ring: 4 x 344 KB = 1.4 MB/rg < 4 MB XCD L2
#define SLAB  172032  // 128 rows * 1344 cols, elements per rg slab
#define FSTR  160     // flag array stride (ints), 640 B -> no cross-line sharing

// tiles (r11-proven): L0 96-col x7 blocks, L1 48-col x14 blocks
#define NL0B  7
#define NL1B  14
#define NBLK  (8 * (NL0B + NL1B))   // 168

typedef __hip_bfloat16 bf16;
typedef unsigned short ush;
typedef unsigned long long u64;
using frag8 = __attribute__((ext_vector_type(8))) short;  // 8 bf16
using f32x4 = __attribute__((ext_vector_type(4))) float;

// ---------------------------------------------------------------- prep kernels

__global__ void prep_xs(const float* __restrict__ xs, bf16* __restrict__ xs_pad) {
    int idx = blockIdx.x * blockDim.x + threadIdx.x;
    if (idx >= T_STEPS * B_SZ * XK) return;
    int k = idx % XK;
    int rb = idx / XK;
    float v = (k < IN_SZ) ? xs[(size_t)rb * IN_SZ + k] : 0.f;
    xs_pad[idx] = __float2bfloat16(v);
}

__global__ void pack_w0(const float* __restrict__ Wih, const float* __restrict__ Whh,
                        bf16* __restrict__ Wc) {
    int idx = blockIdx.x * blockDim.x + threadIdx.x;
    if (idx >= N0PAD * K0) return;
    int j = idx / K0, k = idx % K0;
    float v = 0.f;
    if (j < H_SZ) {
        if (k < IN_SZ)                      v = Wih[(size_t)j * IN_SZ + k];
        else if (k >= XK && k < XK + H_SZ)  v = Whh[(size_t)j * H_SZ + (k - XK)];
    }
    Wc[idx] = __float2bfloat16(v);
}

__global__ void pack_w1(const float* __restrict__ Wih, const float* __restrict__ Whh,
                        bf16* __restrict__ Wc) {
    int idx = blockIdx.x * blockDim.x + threadIdx.x;
    if (idx >= N1PAD * K1) return;
    int j = idx / K1, k = idx % K1;
    float v = 0.f;
    if (j < H_SZ) {
        if (k < H_SZ)                          v = Wih[(size_t)j * H_SZ + k];
        else if (k >= 672 && k < 672 + H_SZ)   v = Whh[(size_t)j * H_SZ + (k - 672)];
    }
    Wc[idx] = __float2bfloat16(v);
}

__global__ void pack_bias(const float* __restrict__ bi, const float* __restrict__ bh,
                          float* __restrict__ b, int n) {
    int j = blockIdx.x * blockDim.x + threadIdx.x;
    if (j >= n) return;
    b[j] = (j < H_SZ) ? (bi[j] + bh[j]) : 0.f;
}

// ---------------------------------------------------------------- persistent RNN
// r15 structure (RING=4 L2-resident ring, no fences) with the L1-staleness fix:
//   ALL h-slab loads are RELAXED AGENT-SCOPE ATOMIC loads (sc0: bypass L1,
//   read the XCD L2 directly) — the same mechanism that makes flag polls see
//   remote updates. This guarantees freshness structurally without ever
//   invalidating the L2 (preserving the dirty-resident ring), and the
//   compiler still tracks vmcnt for scheduling (MLP preserved).
//   r15's failure (absmax 0.043, barely over) was stale L1 lines after the
//   fence removal; ordering math at R=4 was sound and is kept verbatim:
//     L0 phase p: RAW fL0[p-1]>=7; WAR fL1[p-3]>=14 (slot p%4 readers done).
//     L1 phase q: RAW fL0[q-1]>=7 (early), fL1[q-1]>=14 (late, after h0 half).
// Producer stores: plain coalesced (dirty in local XCD L2; rg<->XCD
// co-location validated r13); per-wave vmcnt(0) drain at the epilogue
// barrier; thread0 publishes relaxed agent fetch_add.

__device__ __forceinline__ void tanh_store(ush* dst, float x) {
    x = fminf(fmaxf(x, -15.f), 15.f);
    float e = __expf(2.f * x);
    bf16 hb = __float2bfloat16((e - 1.f) / (e + 1.f));
    *dst = *(ush*)&hb;     // plain store: coalesced, dirty in local (XCD) L2
}

__device__ __forceinline__ uint4 ld_slab(const bf16* p) {
    // 16 B as two 8-B relaxed agent atomic loads: sc0 (L1-bypass), L2-served
    const u64* q = (const u64*)p;
    u64 lo = __hip_atomic_load(q,     __ATOMIC_RELAXED, __HIP_MEMORY_SCOPE_AGENT);
    u64 hi = __hip_atomic_load(q + 1, __ATOMIC_RELAXED, __HIP_MEMORY_SCOPE_AGENT);
    uint4 r;
    r.x = (unsigned)lo; r.y = (unsigned)(lo >> 32);
    r.z = (unsigned)hi; r.w = (unsigned)(hi >> 32);
    return r;
}

__device__ __forceinline__ void poll_ge(int* p, int need) {
    while (__hip_atomic_load(p, __ATOMIC_RELAXED, __HIP_MEMORY_SCOPE_AGENT) < need)
        __builtin_amdgcn_s_sleep(2);
}

__global__ __launch_bounds__(512, 2) void persist(
    const bf16* __restrict__ xs_pad, const bf16* __restrict__ Wc0,
    const bf16* __restrict__ Wc1, const float* __restrict__ b0,
    const float* __restrict__ b1, bf16* __restrict__ Sring,
    int* __restrict__ flags)
{
    extern __shared__ ush Wlds[];
    const int bid  = blockIdx.x;
    const int rg   = bid & 7;
    const int c8   = bid >> 3;
    const bool isL0 = (c8 < NL0B);
    const int tid  = threadIdx.x;
    const int wv   = tid >> 6;
    const int lane = tid & 63;
    const int q8   = (lane >> 4) * 8;    // fragment k offset (elements)
    const int l15  = lane & 15;

    // ---- stage W slice into LDS in fragment order (once) ----
    if (isL0) {
        const int col0 = c8 * 96;
        for (int g = wv; g < 144; g += 8) {           // g = kc*6 + ct
            int kc = g / 6, ct = g % 6;
            const bf16* src = Wc0 + (size_t)(col0 + ct*16 + l15) * K0 + kc*32 + q8;
            *(uint4*)&Wlds[g*512 + lane*8] = *(const uint4*)src;
        }
    } else {
        const int col0 = (c8 - NL0B) * 48;
        for (int g = wv; g < 126; g += 8) {           // g = kc*3 + ct
            int kc = g / 3, ct = g % 3;
            const bf16* src = Wc1 + (size_t)(col0 + ct*16 + l15) * K1 + kc*32 + q8;
            *(uint4*)&Wlds[g*512 + lane*8] = *(const uint4*)src;
        }
    }
    __syncthreads();

    const int loc = wv * 16 + l15;      // this wave's A-fragment row (16 rows/wave)
    bf16* const ringbase = Sring + (size_t)rg * RING * SLAB;
    int*  const fL0 = flags + rg * FSTR;          // NL0B publishers
    int*  const fL1 = flags + (8 + rg) * FSTR;    // NL1B publishers

    if (isL0) {
        const int col0 = c8 * 96;
        float bias[6];
        #pragma unroll
        for (int ct = 0; ct < 6; ++ct) bias[ct] = b0[col0 + ct*16 + l15];

        for (int p = 0; p < 128; ++p) {
            const bf16* rsl = ringbase + (size_t)((p + RING - 1) % RING) * SLAB;
            bf16*       wsl = ringbase + (size_t)(p % RING) * SLAB;

            // xs chunks: input-static, issue before any wait (plain loads OK)
            const bf16* xr = xs_pad + ((size_t)p * B_SZ + rg*128 + loc) * XK + q8;
            uint4 xbuf[3];
            #pragma unroll
            for (int i = 0; i < 3; ++i) xbuf[i] = *(const uint4*)(xr + i*32);

            if (tid == 0) {
                if (p > 0)  poll_ge(&fL0[p-1], NL0B);   // RAW: h0(p-1) ready
                if (p >= 4) poll_ge(&fL1[p-3], NL1B);   // WAR: slot p%4 readers done
            }
            __syncthreads();

            // A = [x_t(96) | h0(p-1)(672)], C = h0(p) -> slab cols [0,672)
            const bf16* hr = rsl + (size_t)loc * K1 + q8;
            uint4 hbuf[21];
            #pragma unroll
            for (int i = 0; i < 21; ++i) hbuf[i] = ld_slab(hr + i*32);

            f32x4 acc[6] = {};
            #pragma unroll
            for (int kc = 0; kc < 24; ++kc) {
                frag8 af = (kc < 3) ? *(const frag8*)&xbuf[kc]
                                    : *(const frag8*)&hbuf[kc-3];
                #pragma unroll
                for (int ct = 0; ct < 6; ++ct) {
                    frag8 wf = *(const frag8*)&Wlds[(kc*6+ct)*512 + lane*8];
                    acc[ct] = __builtin_amdgcn_mfma_f32_16x16x32_bf16(
                        af, wf, acc[ct], 0, 0, 0);
                }
            }
            const int rbase = wv*16 + (lane>>4)*4;
            #pragma unroll
            for (int ct = 0; ct < 6; ++ct) {
                const int col = col0 + ct*16 + l15;
                if (col < H_SZ) {
                    #pragma unroll
                    for (int i = 0; i < 4; ++i)
                        tanh_store((ush*)(wsl + (size_t)(rbase+i)*K1 + col),
                                   acc[ct][i] + bias[ct]);
                }
            }
            __syncthreads();   // per-wave vmcnt(0) drain: stores in L2 pre-publish
            if (tid == 0)
                __hip_atomic_fetch_add(&fL0[p], 1, __ATOMIC_RELAXED,
                                       __HIP_MEMORY_SCOPE_AGENT);
        }
    } else {
        const int col0 = (c8 - NL0B) * 48;
        float bias[3];
        #pragma unroll
        for (int ct = 0; ct < 3; ++ct) bias[ct] = b1[col0 + ct*16 + l15];

        for (int q = 1; q <= 128; ++q) {
            const bf16* rsl = ringbase + (size_t)((q + RING - 1) % RING) * SLAB;
            bf16*       wsl = ringbase + (size_t)(q % RING) * SLAB;
            const bf16* ar  = rsl + (size_t)loc * K1 + q8;

            // ---- stage 1: h0 half (gated only by fL0; L0 runs ahead) ----
            if (tid == 0) poll_ge(&fL0[q-1], NL0B);
            __syncthreads();

            uint4 h0buf[21];
            #pragma unroll
            for (int i = 0; i < 21; ++i) h0buf[i] = ld_slab(ar + i*32);
            f32x4 acc[3] = {};
            #pragma unroll
            for (int kc = 0; kc < 21; ++kc) {
                frag8 af = *(const frag8*)&h0buf[kc];
                #pragma unroll
                for (int ct = 0; ct < 3; ++ct) {
                    frag8 wf = *(const frag8*)&Wlds[(kc*3+ct)*512 + lane*8];
                    acc[ct] = __builtin_amdgcn_mfma_f32_16x16x32_bf16(
                        af, wf, acc[ct], 0, 0, 0);
                }
            }

            // ---- stage 2: h1 half (the true serial gate, polled LATE) ----
            if (q > 1) {
                if (tid == 0) poll_ge(&fL1[q-1], NL1B);
                __syncthreads();
            }
            uint4 h1buf[21];
            #pragma unroll
            for (int i = 0; i < 21; ++i) h1buf[i] = ld_slab(ar + (21 + i)*32);
            #pragma unroll
            for (int kc = 21; kc < 42; ++kc) {
                frag8 af = *(const frag8*)&h1buf[kc-21];
                #pragma unroll
                for (int ct = 0; ct < 3; ++ct) {
                    frag8 wf = *(const frag8*)&Wlds[(kc*3+ct)*512 + lane*8];
                    acc[ct] = __builtin_amdgcn_mfma_f32_16x16x32_bf16(
                        af, wf, acc[ct], 0, 0, 0);
                }
            }
            const int rbase = wv*16 + (lane>>4)*4;
            #pragma unroll
            for (int ct = 0; ct < 3; ++ct) {
                const int col = col0 + ct*16 + l15;
                if (col < H_SZ) {
                    #pragma unroll
                    for (int i = 0; i < 4; ++i)
                        tanh_store((ush*)(wsl + (size_t)(rbase+i)*K1 + 672 + col),
                                   acc[ct][i] + bias[ct]);
                }
            }
            __syncthreads();   // per-wave vmcnt(0) drain: stores in L2 pre-publish
            if (tid == 0)
                __hip_atomic_fetch_add(&fL1[q], 1, __ATOMIC_RELAXED,
                                       __HIP_MEMORY_SCOPE_AGENT);
        }
    }
}

// ---------------------------------------------------------------- classifier
__global__ __launch_bounds__(256) void classifier(
    const bf16* __restrict__ Sring, const float* __restrict__ Wout,
    const float* __restrict__ bout, float* __restrict__ out)
{
    const int wave = threadIdx.x >> 6, lane = threadIdx.x & 63;
    const int row = blockIdx.x * 4 + wave;
    const int rg = row >> 7, loc = row & 127;
    const bf16* h1 = Sring + ((size_t)rg * RING + (128 % RING)) * SLAB
                     + (size_t)loc * K1 + 672;
    float acc[OUT_SZ] = {0.f, 0.f, 0.f, 0.f, 0.f};
    for (int k = lane; k < H_SZ; k += 64) {
        float h = __bfloat162float(h1[k]);
        #pragma unroll
        for (int o = 0; o < OUT_SZ; ++o) acc[o] += h * Wout[(size_t)o * H_SZ + k];
    }
    #pragma unroll
    for (int o = 0; o < OUT_SZ; ++o) {
        float v = acc[o];
        #pragma unroll
        for (int off = 32; off; off >>= 1) v += __shfl_down(v, off, 64);
        if (lane == 0) out[(size_t)row * OUT_SZ + o] = v + bout[o];
    }
}

// ---------------------------------------------------------------- launch

extern "C" void kernel_launch(void* const* d_in, const int* in_sizes, int n_in,
                              void* d_out, int out_size, void* d_ws, size_t ws_size,
                              hipStream_t stream) {
    const float* xs   = (const float*)d_in[0];
    const float* Wih0 = (const float*)d_in[1];
    const float* Whh0 = (const float*)d_in[2];
    const float* bih0 = (const float*)d_in[3];
    const float* bhh0 = (const float*)d_in[4];
    const float* Wih1 = (const float*)d_in[5];
    const float* Whh1 = (const float*)d_in[6];
    const float* bih1 = (const float*)d_in[7];
    const float* bhh1 = (const float*)d_in[8];
    const float* Wout = (const float*)d_in[9];
    const float* bout = (const float*)d_in[10];
    float* out = (float*)d_out;

    char* ws = (char*)d_ws;
    size_t off = 0;
    bf16* xs_pad = (bf16*)(ws + off); off += (size_t)T_STEPS * B_SZ * XK * 2;
    bf16* Wc0    = (bf16*)(ws + off); off += (size_t)N0PAD * K0 * 2;
    bf16* Wc1    = (bf16*)(ws + off); off += (size_t)N1PAD * K1 * 2;
    float* b0    = (float*)(ws + off); off += (size_t)N0PAD * 4;
    float* b1    = (float*)(ws + off); off += (size_t)N1PAD * 4;
    bf16* Sring  = (bf16*)(ws + off); off += (size_t)8 * RING * SLAB * 2;
    int*  flags  = (int*)(ws + off);  off += (size_t)16 * FSTR * 4;

    // ring (incl. zero-state slots + pad columns) and both flag arrays start zero
    hipMemsetAsync(Sring, 0, (size_t)8 * RING * SLAB * 2, stream);
    hipMemsetAsync(flags, 0, (size_t)16 * FSTR * 4, stream);

    prep_xs <<<(T_STEPS * B_SZ * XK + 255) / 256, 256, 0, stream>>>(xs, xs_pad);
    pack_w0 <<<(N0PAD * K0 + 255) / 256, 256, 0, stream>>>(Wih0, Whh0, Wc0);
    pack_w1 <<<(N1PAD * K1 + 255) / 256, 256, 0, stream>>>(Wih1, Whh1, Wc1);
    pack_bias<<<(N0PAD + 255) / 256, 256, 0, stream>>>(bih0, bhh0, b0, N0PAD);
    pack_bias<<<(N1PAD + 255) / 256, 256, 0, stream>>>(bih1, bhh1, b1, N1PAD);

    // dynamic LDS: max(W0 slice 147456 B, W1 slice 129024 B)
    hipFuncSetAttribute((const void*)persist,
                        hipFuncAttributeMaxDynamicSharedMemorySize, 147456);
    void* args[] = { (void*)&xs_pad, (void*)&Wc0, (void*)&Wc1, (void*)&b0,
                     (void*)&b1, (void*)&Sring, (void*)&flags };
    hipLaunchCooperativeKernel((const void*)persist, dim3(NBLK), dim3(512),
                               args, 147456, stream);

    classifier<<<B_SZ / 4, 256, 0, stream>>>(Sring, Wout, bout, out);
}

// Round 18
// 1786.039 us; speedup vs baseline: 1.5461x; 1.5461x over previous
//
#include <hip/hip_runtime.h>
#include <hip/hip_bf16.h>

#define T_STEPS 128
#define B_SZ    1024
#define IN_SZ   47
#define H_SZ    646
#define OUT_SZ  5

#define XK    96      // xs padded row stride (47 -> 96)
#define K0    768     // layer0 K = 96 + 672
#define K1    1344    // layer1 K = 672 + 672 (also the state-slab row stride)
#define N0PAD 704     // L0 packed-W cols (11 * 64, zero-padded)
#define N1PAD 672     // L1 packed-W cols
#define RING  4       // L2-resident ring: 4 x 344 KB = 1.4 MB/rg < 4 MB XCD L2
#define SLAB  172032  // 128 rows * 1344 cols, elements per rg slab
#define FSTR  160     // flag array stride (ints), 640 B -> no cross-line sharing

// tiles (r11-proven): L0 96-col x7 blocks, L1 48-col x14 blocks
#define NL0B  7
#define NL1B  14
#define NBLK  (8 * (NL0B + NL1B))   // 168

typedef __hip_bfloat16 bf16;
typedef unsigned short ush;
using frag8 = __attribute__((ext_vector_type(8))) short;  // 8 bf16
using f32x4 = __attribute__((ext_vector_type(4))) float;

// ---------------------------------------------------------------- prep kernels

__global__ void prep_xs(const float* __restrict__ xs, bf16* __restrict__ xs_pad) {
    int idx = blockIdx.x * blockDim.x + threadIdx.x;
    if (idx >= T_STEPS * B_SZ * XK) return;
    int k = idx % XK;
    int rb = idx / XK;
    float v = (k < IN_SZ) ? xs[(size_t)rb * IN_SZ + k] : 0.f;
    xs_pad[idx] = __float2bfloat16(v);
}

__global__ void pack_w0(const float* __restrict__ Wih, const float* __restrict__ Whh,
                        bf16* __restrict__ Wc) {
    int idx = blockIdx.x * blockDim.x + threadIdx.x;
    if (idx >= N0PAD * K0) return;
    int j = idx / K0, k = idx % K0;
    float v = 0.f;
    if (j < H_SZ) {
        if (k < IN_SZ)                      v = Wih[(size_t)j * IN_SZ + k];
        else if (k >= XK && k < XK + H_SZ)  v = Whh[(size_t)j * H_SZ + (k - XK)];
    }
    Wc[idx] = __float2bfloat16(v);
}

__global__ void pack_w1(const float* __restrict__ Wih, const float* __restrict__ Whh,
                        bf16* __restrict__ Wc) {
    int idx = blockIdx.x * blockDim.x + threadIdx.x;
    if (idx >= N1PAD * K1) return;
    int j = idx / K1, k = idx % K1;
    float v = 0.f;
    if (j < H_SZ) {
        if (k < H_SZ)                          v = Wih[(size_t)j * H_SZ + k];
        else if (k >= 672 && k < 672 + H_SZ)   v = Whh[(size_t)j * H_SZ + (k - 672)];
    }
    Wc[idx] = __float2bfloat16(v);
}

__global__ void pack_bias(const float* __restrict__ bi, const float* __restrict__ bh,
                          float* __restrict__ b, int n) {
    int j = blockIdx.x * blockDim.x + threadIdx.x;
    if (j >= n) return;
    b[j] = (j < H_SZ) ? (bi[j] + bh[j]) : 0.f;
}

// ---------------------------------------------------------------- persistent RNN
// r16 validated: RING=4 L2-resident ring (FETCH 204->30 MB) + per-load L1
// bypass (sc0) = CORRECT; its cost was the uncoalesced 8-B atomic-load path.
// Round 18: same semantics, efficient encoding — each 21-chunk K-half is
// loaded by ONE inline-asm batch of 21 coalesced `global_load_dwordx4 ... sc0`
// (L1-bypassing, L2-served, device-coherent: the glc successor) off a single
// base register with immediate offsets, one s_waitcnt vmcnt(0) at the end
// (21-deep MLP per batch). No fences, no cache invalidation anywhere.
// Ordering identical to r15/r16 (r16-passed):
//   L0 phase p: RAW fL0[p-1]>=7; WAR fL1[p-3]>=14 (slot p%4 readers done).
//   L1 phase q: RAW fL0[q-1]>=7 (early), fL1[q-1]>=14 (late, after h0 half).
// Producer stores plain (dirty local L2; rg<->XCD co-location validated
// r13/r16); per-wave vmcnt(0) drain at epilogue barrier; thread0 relaxed
// agent publish; xs/W/bias are pre-kernel-written (plain loads fine).

__device__ __forceinline__ void tanh_store(ush* dst, float x) {
    x = fminf(fmaxf(x, -15.f), 15.f);
    float e = __expf(2.f * x);
    bf16 hb = __float2bfloat16((e - 1.f) / (e + 1.f));
    *dst = *(ush*)&hb;     // plain store: coalesced, dirty in local (XCD) L2
}

// 21 contiguous 64-B chunks (per lane-quad pattern), L1-bypassing, coalesced.
__device__ __forceinline__ void ld_sc0_21(const bf16* base, uint4 (&b)[21]) {
    asm volatile(
        "global_load_dwordx4 %0, %[a], off sc0\n\t"
        "global_load_dwordx4 %1, %[a], off offset:64 sc0\n\t"
        "global_load_dwordx4 %2, %[a], off offset:128 sc0\n\t"
        "global_load_dwordx4 %3, %[a], off offset:192 sc0\n\t"
        "global_load_dwordx4 %4, %[a], off offset:256 sc0\n\t"
        "global_load_dwordx4 %5, %[a], off offset:320 sc0\n\t"
        "global_load_dwordx4 %6, %[a], off offset:384 sc0\n\t"
        "global_load_dwordx4 %7, %[a], off offset:448 sc0\n\t"
        "global_load_dwordx4 %8, %[a], off offset:512 sc0\n\t"
        "global_load_dwordx4 %9, %[a], off offset:576 sc0\n\t"
        "global_load_dwordx4 %10, %[a], off offset:640 sc0\n\t"
        "global_load_dwordx4 %11, %[a], off offset:704 sc0\n\t"
        "global_load_dwordx4 %12, %[a], off offset:768 sc0\n\t"
        "global_load_dwordx4 %13, %[a], off offset:832 sc0\n\t"
        "global_load_dwordx4 %14, %[a], off offset:896 sc0\n\t"
        "global_load_dwordx4 %15, %[a], off offset:960 sc0\n\t"
        "global_load_dwordx4 %16, %[a], off offset:1024 sc0\n\t"
        "global_load_dwordx4 %17, %[a], off offset:1088 sc0\n\t"
        "global_load_dwordx4 %18, %[a], off offset:1152 sc0\n\t"
        "global_load_dwordx4 %19, %[a], off offset:1216 sc0\n\t"
        "global_load_dwordx4 %20, %[a], off offset:1280 sc0\n\t"
        "s_waitcnt vmcnt(0)"
        : "=&v"(b[0]), "=&v"(b[1]), "=&v"(b[2]), "=&v"(b[3]), "=&v"(b[4]),
          "=&v"(b[5]), "=&v"(b[6]), "=&v"(b[7]), "=&v"(b[8]), "=&v"(b[9]),
          "=&v"(b[10]), "=&v"(b[11]), "=&v"(b[12]), "=&v"(b[13]), "=&v"(b[14]),
          "=&v"(b[15]), "=&v"(b[16]), "=&v"(b[17]), "=&v"(b[18]), "=&v"(b[19]),
          "=&v"(b[20])
        : [a] "v"(base)
        : "memory");
}

__device__ __forceinline__ void poll_ge(int* p, int need) {
    while (__hip_atomic_load(p, __ATOMIC_RELAXED, __HIP_MEMORY_SCOPE_AGENT) < need)
        __builtin_amdgcn_s_sleep(2);
}

__global__ __launch_bounds__(512, 2) void persist(
    const bf16* __restrict__ xs_pad, const bf16* __restrict__ Wc0,
    const bf16* __restrict__ Wc1, const float* __restrict__ b0,
    const float* __restrict__ b1, bf16* __restrict__ Sring,
    int* __restrict__ flags)
{
    extern __shared__ ush Wlds[];
    const int bid  = blockIdx.x;
    const int rg   = bid & 7;
    const int c8   = bid >> 3;
    const bool isL0 = (c8 < NL0B);
    const int tid  = threadIdx.x;
    const int wv   = tid >> 6;
    const int lane = tid & 63;
    const int q8   = (lane >> 4) * 8;    // fragment k offset (elements)
    const int l15  = lane & 15;

    // ---- stage W slice into LDS in fragment order (once) ----
    if (isL0) {
        const int col0 = c8 * 96;
        for (int g = wv; g < 144; g += 8) {           // g = kc*6 + ct
            int kc = g / 6, ct = g % 6;
            const bf16* src = Wc0 + (size_t)(col0 + ct*16 + l15) * K0 + kc*32 + q8;
            *(uint4*)&Wlds[g*512 + lane*8] = *(const uint4*)src;
        }
    } else {
        const int col0 = (c8 - NL0B) * 48;
        for (int g = wv; g < 126; g += 8) {           // g = kc*3 + ct
            int kc = g / 3, ct = g % 3;
            const bf16* src = Wc1 + (size_t)(col0 + ct*16 + l15) * K1 + kc*32 + q8;
            *(uint4*)&Wlds[g*512 + lane*8] = *(const uint4*)src;
        }
    }
    __syncthreads();

    const int loc = wv * 16 + l15;      // this wave's A-fragment row (16 rows/wave)
    bf16* const ringbase = Sring + (size_t)rg * RING * SLAB;
    int*  const fL0 = flags + rg * FSTR;          // NL0B publishers
    int*  const fL1 = flags + (8 + rg) * FSTR;    // NL1B publishers

    if (isL0) {
        const int col0 = c8 * 96;
        float bias[6];
        #pragma unroll
        for (int ct = 0; ct < 6; ++ct) bias[ct] = b0[col0 + ct*16 + l15];

        for (int p = 0; p < 128; ++p) {
            const bf16* rsl = ringbase + (size_t)((p + RING - 1) % RING) * SLAB;
            bf16*       wsl = ringbase + (size_t)(p % RING) * SLAB;

            // xs chunks: input-static, issue before any wait (plain loads OK)
            const bf16* xr = xs_pad + ((size_t)p * B_SZ + rg*128 + loc) * XK + q8;
            uint4 xbuf[3];
            #pragma unroll
            for (int i = 0; i < 3; ++i) xbuf[i] = *(const uint4*)(xr + i*32);

            if (tid == 0) {
                if (p > 0)  poll_ge(&fL0[p-1], NL0B);   // RAW: h0(p-1) ready
                if (p >= 4) poll_ge(&fL1[p-3], NL1B);   // WAR: slot p%4 readers done
            }
            __syncthreads();

            // A = [x_t(96) | h0(p-1)(672)], C = h0(p) -> slab cols [0,672)
            uint4 hbuf[21];
            ld_sc0_21(rsl + (size_t)loc * K1 + q8, hbuf);

            f32x4 acc[6] = {};
            #pragma unroll
            for (int kc = 0; kc < 24; ++kc) {
                frag8 af = (kc < 3) ? *(const frag8*)&xbuf[kc]
                                    : *(const frag8*)&hbuf[kc-3];
                #pragma unroll
                for (int ct = 0; ct < 6; ++ct) {
                    frag8 wf = *(const frag8*)&Wlds[(kc*6+ct)*512 + lane*8];
                    acc[ct] = __builtin_amdgcn_mfma_f32_16x16x32_bf16(
                        af, wf, acc[ct], 0, 0, 0);
                }
            }
            const int rbase = wv*16 + (lane>>4)*4;
            #pragma unroll
            for (int ct = 0; ct < 6; ++ct) {
                const int col = col0 + ct*16 + l15;
                if (col < H_SZ) {
                    #pragma unroll
                    for (int i = 0; i < 4; ++i)
                        tanh_store((ush*)(wsl + (size_t)(rbase+i)*K1 + col),
                                   acc[ct][i] + bias[ct]);
                }
            }
            __syncthreads();   // per-wave vmcnt(0) drain: stores in L2 pre-publish
            if (tid == 0)
                __hip_atomic_fetch_add(&fL0[p], 1, __ATOMIC_RELAXED,
                                       __HIP_MEMORY_SCOPE_AGENT);
        }
    } else {
        const int col0 = (c8 - NL0B) * 48;
        float bias[3];
        #pragma unroll
        for (int ct = 0; ct < 3; ++ct) bias[ct] = b1[col0 + ct*16 + l15];

        for (int q = 1; q <= 128; ++q) {
            const bf16* rsl = ringbase + (size_t)((q + RING - 1) % RING) * SLAB;
            bf16*       wsl = ringbase + (size_t)(q % RING) * SLAB;
            const bf16* ar  = rsl + (size_t)loc * K1 + q8;

            // ---- stage 1: h0 half (gated only by fL0; L0 runs ahead) ----
            if (tid == 0) poll_ge(&fL0[q-1], NL0B);
            __syncthreads();

            uint4 h0buf[21];
            ld_sc0_21(ar, h0buf);
            f32x4 acc[3] = {};
            #pragma unroll
            for (int kc = 0; kc < 21; ++kc) {
                frag8 af = *(const frag8*)&h0buf[kc];
                #pragma unroll
                for (int ct = 0; ct < 3; ++ct) {
                    frag8 wf = *(const frag8*)&Wlds[(kc*3+ct)*512 + lane*8];
                    acc[ct] = __builtin_amdgcn_mfma_f32_16x16x32_bf16(
                        af, wf, acc[ct], 0, 0, 0);
                }
            }

            // ---- stage 2: h1 half (the true serial gate, polled LATE) ----
            if (q > 1) {
                if (tid == 0) poll_ge(&fL1[q-1], NL1B);
                __syncthreads();
            }
            uint4 h1buf[21];
            ld_sc0_21(ar + 672, h1buf);
            #pragma unroll
            for (int kc = 21; kc < 42; ++kc) {
                frag8 af = *(const frag8*)&h1buf[kc-21];
                #pragma unroll
                for (int ct = 0; ct < 3; ++ct) {
                    frag8 wf = *(const frag8*)&Wlds[(kc*3+ct)*512 + lane*8];
                    acc[ct] = __builtin_amdgcn_mfma_f32_16x16x32_bf16(
                        af, wf, acc[ct], 0, 0, 0);
                }
            }
            const int rbase = wv*16 + (lane>>4)*4;
            #pragma unroll
            for (int ct = 0; ct < 3; ++ct) {
                const int col = col0 + ct*16 + l15;
                if (col < H_SZ) {
                    #pragma unroll
                    for (int i = 0; i < 4; ++i)
                        tanh_store((ush*)(wsl + (size_t)(rbase+i)*K1 + 672 + col),
                                   acc[ct][i] + bias[ct]);
                }
            }
            __syncthreads();   // per-wave vmcnt(0) drain: stores in L2 pre-publish
            if (tid == 0)
                __hip_atomic_fetch_add(&fL1[q], 1, __ATOMIC_RELAXED,
                                       __HIP_MEMORY_SCOPE_AGENT);
        }
    }
}

// ---------------------------------------------------------------- classifier
__global__ __launch_bounds__(256) void classifier(
    const bf16* __restrict__ Sring, const float* __restrict__ Wout,
    const float* __restrict__ bout, float* __restrict__ out)
{
    const int wave = threadIdx.x >> 6, lane = threadIdx.x & 63;
    const int row = blockIdx.x * 4 + wave;
    const int rg = row >> 7, loc = row & 127;
    const bf16* h1 = Sring + ((size_t)rg * RING + (128 % RING)) * SLAB
                     + (size_t)loc * K1 + 672;
    float acc[OUT_SZ] = {0.f, 0.f, 0.f, 0.f, 0.f};
    for (int k = lane; k < H_SZ; k += 64) {
        float h = __bfloat162float(h1[k]);
        #pragma unroll
        for (int o = 0; o < OUT_SZ; ++o) acc[o] += h * Wout[(size_t)o * H_SZ + k];
    }
    #pragma unroll
    for (int o = 0; o < OUT_SZ; ++o) {
        float v = acc[o];
        #pragma unroll
        for (int off = 32; off; off >>= 1) v += __shfl_down(v, off, 64);
        if (lane == 0) out[(size_t)row * OUT_SZ + o] = v + bout[o];
    }
}

// ---------------------------------------------------------------- launch

extern "C" void kernel_launch(void* const* d_in, const int* in_sizes, int n_in,
                              void* d_out, int out_size, void* d_ws, size_t ws_size,
                              hipStream_t stream) {
    const float* xs   = (const float*)d_in[0];
    const float* Wih0 = (const float*)d_in[1];
    const float* Whh0 = (const float*)d_in[2];
    const float* bih0 = (const float*)d_in[3];
    const float* bhh0 = (const float*)d_in[4];
    const float* Wih1 = (const float*)d_in[5];
    const float* Whh1 = (const float*)d_in[6];
    const float* bih1 = (const float*)d_in[7];
    const float* bhh1 = (const float*)d_in[8];
    const float* Wout = (const float*)d_in[9];
    const float* bout = (const float*)d_in[10];
    float* out = (float*)d_out;

    char* ws = (char*)d_ws;
    size_t off = 0;
    bf16* xs_pad = (bf16*)(ws + off); off += (size_t)T_STEPS * B_SZ * XK * 2;
    bf16* Wc0    = (bf16*)(ws + off); off += (size_t)N0PAD * K0 * 2;
    bf16* Wc1    = (bf16*)(ws + off); off += (size_t)N1PAD * K1 * 2;
    float* b0    = (float*)(ws + off); off += (size_t)N0PAD * 4;
    float* b1    = (float*)(ws + off); off += (size_t)N1PAD * 4;
    bf16* Sring  = (bf16*)(ws + off); off += (size_t)8 * RING * SLAB * 2;
    int*  flags  = (int*)(ws + off);  off += (size_t)16 * FSTR * 4;

    // ring (incl. zero-state slots + pad columns) and both flag arrays start zero
    hipMemsetAsync(Sring, 0, (size_t)8 * RING * SLAB * 2, stream);
    hipMemsetAsync(flags, 0, (size_t)16 * FSTR * 4, stream);

    prep_xs <<<(T_STEPS * B_SZ * XK + 255) / 256, 256, 0, stream>>>(xs, xs_pad);
    pack_w0 <<<(N0PAD * K0 + 255) / 256, 256, 0, stream>>>(Wih0, Whh0, Wc0);
    pack_w1 <<<(N1PAD * K1 + 255) / 256, 256, 0, stream>>>(Wih1, Whh1, Wc1);
    pack_bias<<<(N0PAD + 255) / 256, 256, 0, stream>>>(bih0, bhh0, b0, N0PAD);
    pack_bias<<<(N1PAD + 255) / 256, 256, 0, stream>>>(bih1, bhh1, b1, N1PAD);

    // dynamic LDS: max(W0 slice 147456 B, W1 slice 129024 B)
    hipFuncSetAttribute((const void*)persist,
                        hipFuncAttributeMaxDynamicSharedMemorySize, 147456);
    void* args[] = { (void*)&xs_pad, (void*)&Wc0, (void*)&Wc1, (void*)&b0,
                     (void*)&b1, (void*)&Sring, (void*)&flags };
    hipLaunchCooperativeKernel((const void*)persist, dim3(NBLK), dim3(512),
                               args, 147456, stream);

    classifier<<<B_SZ / 4, 256, 0, stream>>>(Sring, Wout, bout, out);
}